// Round 1
// baseline (654.884 us; speedup 1.0000x reference)
//
#include <hip/hip_runtime.h>

// GCNCheb on MI355X.
// out[b,n,fo] = sum_k (L^k x)[b,n,:] . w_eff[k] + bias,  w_eff folded from Cheb recurrence.
// 3 passes of Y = L @ X (M=8192, K=8192, Ncols=128) in bf16 MFMA, fp32 accumulate.

typedef __bf16 bf16;
typedef bf16 bf16x8 __attribute__((ext_vector_type(8)));
typedef bf16 bf16x4 __attribute__((ext_vector_type(4)));
typedef float f32x4 __attribute__((ext_vector_type(4)));

static_assert(sizeof(bf16x8) == 16, "bf16x8 must be 16B");

#define N_DIM 8192
#define NCOLS 128            // B * F_IN = 4 * 32
#define BM 128
#define BK 32
#define SPLITS 8
#define KCHUNK (N_DIM / SPLITS)   // 1024
#define LDS_STRIDE 40        // 32 + 8 pad (bf16 elems); row pitch 80 B (16B-aligned)

__device__ inline unsigned short f2bf_bits(float f) {
    bf16 b = (bf16)f;
    return __builtin_bit_cast(unsigned short, b);
}

// ---------------- pack x -> X0^T [128][8192] bf16 ----------------
__global__ __launch_bounds__(256) void pack_x_kernel(
    const float* __restrict__ x, bf16* __restrict__ Xb0) {
    int g = blockIdx.x * 256 + threadIdx.x;    // 0 .. 128*8192
    int n = g & 8191;
    int c = g >> 13;          // 0..127 ; c = b*32 + fi
    int b = c >> 5, fi = c & 31;
    Xb0[(size_t)c * N_DIM + n] = (bf16)x[((size_t)b * N_DIM + n) * 32 + fi];
}

// ---------------- out = bias + x . (w0 - w2)  (pure fp32) ----------------
__global__ __launch_bounds__(256) void init_out_kernel(
    const float* __restrict__ x, const float* __restrict__ w,
    const float* __restrict__ bias, float* __restrict__ out) {
    __shared__ float weff0[32 * 64];
    __shared__ float xs[16 * 32];
    int t = threadIdx.x;
    for (int i = t; i < 2048; i += 256) weff0[i] = w[i] - w[2 * 2048 + i];
    int r0 = blockIdx.x * 16;   // flat row index r = b*8192 + n, 16 rows/block
    for (int i = t; i < 512; i += 256) {
        int lr = i >> 5, fi = i & 31;
        xs[i] = x[(size_t)(r0 + lr) * 32 + fi];
    }
    __syncthreads();
    for (int i = t; i < 1024; i += 256) {
        int lr = i >> 6, fo = i & 63;
        int r = r0 + lr;
        float acc = bias[(size_t)(r & 8191) * 64 + fo];
#pragma unroll
        for (int fi = 0; fi < 32; fi++)
            acc += xs[lr * 32 + fi] * weff0[fi * 64 + fo];
        out[(size_t)r * 64 + fo] = acc;
    }
}

// ---------------- split-K GEMM: part[sp] = L[:, ksplit] @ X^T[:, ksplit]^T ----------------
// A = L (fp32, converted to bf16 in staging), B = Xb (bf16, [col][k] transposed layout).
__global__ __launch_bounds__(256, 2) void gemm_kernel(
    const float* __restrict__ L, const bf16* __restrict__ Xb,
    float* __restrict__ part) {
    __shared__ bf16 As[BM * LDS_STRIDE];      // 10240 B
    __shared__ bf16 Bs[NCOLS * LDS_STRIDE];   // 10240 B

    const int mt = blockIdx.x;           // 0..63
    const int sp = blockIdx.y;           // 0..SPLITS-1
    const int rbase = mt * BM;
    const int kbase = sp * KCHUNK;
    const int t = threadIdx.x;
    const int lane = t & 63;
    const int wave = t >> 6;
    const int wr = wave >> 1, wc = wave & 1;   // 2x2 wave grid, 64x64 each
    const int lm = lane & 15, kq = lane >> 4;

    f32x4 acc[4][4];
    const f32x4 zero = {0.f, 0.f, 0.f, 0.f};
#pragma unroll
    for (int mi = 0; mi < 4; mi++)
#pragma unroll
        for (int ni = 0; ni < 4; ni++) acc[mi][ni] = zero;

    const int arow = t >> 3;   // 0..31 (x4 sweeps -> 128 rows)
    const int ac4 = t & 7;     // float4 column within 32-k tile

    for (int kk = 0; kk < KCHUNK; kk += BK) {
        // stage A: L[rbase..+128][kbase+kk..+32] fp32 -> bf16 LDS
#pragma unroll
        for (int i = 0; i < 4; i++) {
            int row = arow + i * 32;
            const float4 v = *(const float4*)(
                &L[(size_t)(rbase + row) * N_DIM + kbase + kk + ac4 * 4]);
            bf16x4 p;
            p[0] = (bf16)v.x; p[1] = (bf16)v.y; p[2] = (bf16)v.z; p[3] = (bf16)v.w;
            *(bf16x4*)(&As[row * LDS_STRIDE + ac4 * 4]) = p;
        }
        // stage B: Xb[col][kbase+kk..+32] bf16, 16B chunks
#pragma unroll
        for (int j = 0; j < 2; j++) {
            int id = t + 256 * j;          // 0..511
            int col = id >> 2, jj = id & 3;
            const uint4 v = *(const uint4*)(
                &Xb[(size_t)col * N_DIM + kbase + kk + jj * 8]);
            *(uint4*)(&Bs[col * LDS_STRIDE + jj * 8]) = v;
        }
        __syncthreads();

        bf16x8 af[4], bfr[4];
#pragma unroll
        for (int i = 0; i < 4; i++)
            af[i] = *(const bf16x8*)(&As[(wr * 64 + i * 16 + lm) * LDS_STRIDE + kq * 8]);
#pragma unroll
        for (int i = 0; i < 4; i++)
            bfr[i] = *(const bf16x8*)(&Bs[(wc * 64 + i * 16 + lm) * LDS_STRIDE + kq * 8]);
#pragma unroll
        for (int mi = 0; mi < 4; mi++)
#pragma unroll
            for (int ni = 0; ni < 4; ni++)
                acc[mi][ni] = __builtin_amdgcn_mfma_f32_16x16x32_bf16(
                    af[mi], bfr[ni], acc[mi][ni], 0, 0, 0);
        __syncthreads();
    }

    // epilogue: C/D layout col=lane&15, row=(lane>>4)*4+reg  [m89/m91]
    float* P = part + (size_t)sp * N_DIM * NCOLS;
#pragma unroll
    for (int mi = 0; mi < 4; mi++) {
        int row0 = rbase + wr * 64 + mi * 16 + kq * 4;
#pragma unroll
        for (int ni = 0; ni < 4; ni++) {
            int col = wc * 64 + ni * 16 + lm;
#pragma unroll
            for (int r = 0; r < 4; r++)
                P[(size_t)(row0 + r) * NCOLS + col] = acc[mi][ni][r];
        }
    }
}

// ---------------- combine: Y = sum partials; out += Y . w_eff[pass]; XbNext = bf16(Y^T) ----
__global__ __launch_bounds__(256) void combine_kernel(
    const float* __restrict__ part, const float* __restrict__ w,
    float* __restrict__ out, bf16* __restrict__ XbNext, int pass) {
    __shared__ float Yt[128 * 66];     // transposed tile [col][row], pad 66
    __shared__ float weff[32 * 64];
    int t = threadIdx.x;
    int n0 = blockIdx.x * 64;

    for (int i = t; i < 2048; i += 256) {
        float v;
        if (pass == 1)      v = w[1 * 2048 + i] - w[3 * 2048 + i];
        else if (pass == 2) v = 2.f * w[2 * 2048 + i];
        else                v = 2.f * w[3 * 2048 + i];
        weff[i] = v;
    }
    // phase A: sum SPLITS partials, store transposed into LDS
    for (int slot = t; slot < 2048; slot += 256) {
        int row = slot >> 5;       // 0..63
        int c4 = slot & 31;        // float4 col group
        float4 s = {0.f, 0.f, 0.f, 0.f};
#pragma unroll
        for (int sp = 0; sp < SPLITS; sp++) {
            const float4 v = *(const float4*)(
                &part[(size_t)sp * N_DIM * NCOLS + (size_t)(n0 + row) * NCOLS + c4 * 4]);
            s.x += v.x; s.y += v.y; s.z += v.z; s.w += v.w;
        }
        Yt[(c4 * 4 + 0) * 66 + row] = s.x;
        Yt[(c4 * 4 + 1) * 66 + row] = s.y;
        Yt[(c4 * 4 + 2) * 66 + row] = s.z;
        Yt[(c4 * 4 + 3) * 66 + row] = s.w;
    }
    __syncthreads();
    // phase B: bf16 X^T for next pass
    if (pass < 3) {
        int c = t >> 1;
        int nh = (t & 1) * 32;
#pragma unroll
        for (int v4 = 0; v4 < 4; v4++) {
            union { uint4 u; unsigned short s[8]; } pk;
#pragma unroll
            for (int j = 0; j < 8; j++)
                pk.s[j] = f2bf_bits(Yt[c * 66 + nh + v4 * 8 + j]);
            *(uint4*)(&XbNext[(size_t)c * N_DIM + n0 + nh + v4 * 8]) = pk.u;
        }
    }
    // phase C: out[b, n0+n, fo] += sum_fi Y[n, b*32+fi] * weff[fi][fo]
    int b = t >> 6, fo = t & 63;
    for (int n = 0; n < 64; n++) {
        size_t oidx = ((size_t)b * N_DIM + n0 + n) * 64 + fo;
        float accv = out[oidx];
#pragma unroll
        for (int fi = 0; fi < 32; fi++)
            accv += Yt[(b * 32 + fi) * 66 + n] * weff[fi * 64 + fo];
        out[oidx] = accv;
    }
}

extern "C" void kernel_launch(void* const* d_in, const int* in_sizes, int n_in,
                              void* d_out, int out_size, void* d_ws, size_t ws_size,
                              hipStream_t stream) {
    const float* x    = (const float*)d_in[0];   // [4,8192,32]
    const float* L    = (const float*)d_in[1];   // [8192,8192]
    const float* w    = (const float*)d_in[2];   // [4,32,64]
    const float* bias = (const float*)d_in[3];   // [1,8192,64]
    float* out = (float*)d_out;                  // [4,8192,64]

    char* ws = (char*)d_ws;
    bf16* XbA  = (bf16*)ws;                          // 2 MB  (X^T bf16)
    bf16* XbB  = (bf16*)(ws + (2ull << 20));         // 2 MB
    float* part = (float*)(ws + (4ull << 20));       // SPLITS * 4 MB = 32 MB

    pack_x_kernel<<<(NCOLS * N_DIM) / 256, 256, 0, stream>>>(x, XbA);
    init_out_kernel<<<(4 * N_DIM) / 16, 256, 0, stream>>>(x, w, bias, out);

    dim3 ggrid(N_DIM / BM, SPLITS);   // 64 x 8 = 512 WGs
    // pass 1: Y = L x
    gemm_kernel<<<ggrid, 256, 0, stream>>>(L, XbA, part);
    combine_kernel<<<N_DIM / 64, 256, 0, stream>>>(part, w, out, XbB, 1);
    // pass 2: Y = L^2 x
    gemm_kernel<<<ggrid, 256, 0, stream>>>(L, XbB, part);
    combine_kernel<<<N_DIM / 64, 256, 0, stream>>>(part, w, out, XbA, 2);
    // pass 3: Y = L^3 x
    gemm_kernel<<<ggrid, 256, 0, stream>>>(L, XbA, part);
    combine_kernel<<<N_DIM / 64, 256, 0, stream>>>(part, w, out, XbA, 3);
}

// Round 2
// 545.072 us; speedup vs baseline: 1.2015x; 1.2015x over previous
//
#include <hip/hip_runtime.h>

// GCNCheb on MI355X (round 2).
// out[b,n,fo] = sum_k (L^k x)[b,n,:] . w_eff[k] + bias, w_eff folded from Cheb recurrence.
// L pre-converted to bf16 once; 3 passes of Y = Lb @ X (M=8192,K=8192,N=128) with
// global_load_lds(16B) staging, BK=64, XOR-swizzled LDS, split-K=8 + combine.

typedef __bf16 bf16;
typedef bf16 bf16x8 __attribute__((ext_vector_type(8)));
typedef bf16 bf16x4 __attribute__((ext_vector_type(4)));
typedef float f32x4 __attribute__((ext_vector_type(4)));

static_assert(sizeof(bf16x8) == 16, "bf16x8 must be 16B");

#define N_DIM 8192
#define NCOLS 128            // B * F_IN = 4 * 32
#define BM 128
#define BK 64
#define SPLITS 8
#define KCHUNK (N_DIM / SPLITS)   // 1024

__device__ inline unsigned short f2bf_bits(float f) {
    bf16 b = (bf16)f;
    return __builtin_bit_cast(unsigned short, b);
}

__device__ inline void load_lds16(const bf16* g, bf16* l) {
    __builtin_amdgcn_global_load_lds(
        (const __attribute__((address_space(1))) void*)g,
        (__attribute__((address_space(3))) void*)l, 16, 0, 0);
}

// ---------------- L fp32 -> bf16 ----------------
__global__ __launch_bounds__(256) void convert_L_kernel(
    const float* __restrict__ L, bf16* __restrict__ Lb) {
    size_t i = ((size_t)blockIdx.x * 256 + threadIdx.x) * 4;
    const float4 v = *(const float4*)(L + i);
    bf16x4 p;
    p[0] = (bf16)v.x; p[1] = (bf16)v.y; p[2] = (bf16)v.z; p[3] = (bf16)v.w;
    *(bf16x4*)(Lb + i) = p;
}

// ---------------- pack x -> X0^T [128][8192] bf16 ----------------
__global__ __launch_bounds__(256) void pack_x_kernel(
    const float* __restrict__ x, bf16* __restrict__ Xb0) {
    int g = blockIdx.x * 256 + threadIdx.x;    // 0 .. 128*8192
    int n = g & 8191;
    int c = g >> 13;          // 0..127 ; c = b*32 + fi
    int b = c >> 5, fi = c & 31;
    Xb0[(size_t)c * N_DIM + n] = (bf16)x[((size_t)b * N_DIM + n) * 32 + fi];
}

// ---------------- out = bias + x . (w0 - w2)  (pure fp32) ----------------
__global__ __launch_bounds__(256) void init_out_kernel(
    const float* __restrict__ x, const float* __restrict__ w,
    const float* __restrict__ bias, float* __restrict__ out) {
    __shared__ float weff0[32 * 64];
    __shared__ float xs[16 * 32];
    int t = threadIdx.x;
    for (int i = t; i < 2048; i += 256) weff0[i] = w[i] - w[2 * 2048 + i];
    int r0 = blockIdx.x * 16;   // flat row index r = b*8192 + n, 16 rows/block
    for (int i = t; i < 512; i += 256) {
        int lr = i >> 5, fi = i & 31;
        xs[i] = x[(size_t)(r0 + lr) * 32 + fi];
    }
    __syncthreads();
    for (int i = t; i < 1024; i += 256) {
        int lr = i >> 6, fo = i & 63;
        int r = r0 + lr;
        float acc = bias[(size_t)(r & 8191) * 64 + fo];
#pragma unroll
        for (int fi = 0; fi < 32; fi++)
            acc += xs[lr * 32 + fi] * weff0[fi * 64 + fo];
        out[(size_t)r * 64 + fo] = acc;
    }
}

// ---------------- split-K GEMM: part[sp] = Lb[:, kchunk] @ X^T[:, kchunk]^T ----------------
// A = Lb bf16 row-major; B = Xb bf16 [col][k]. global_load_lds(16B) staging.
// LDS layout [row][64] bf16, 128 B rows, NO padding (global_load_lds constraint).
// XOR swizzle applied to the GLOBAL col-block: stored block s at row r holds
// global block s ^ (r & 7); readers XOR the same way. Keeps global coalescing
// (permutation within the 128-B row segment) and balances LDS banks.
__global__ __launch_bounds__(256, 2) void gemm_kernel(
    const bf16* __restrict__ Lb, const bf16* __restrict__ Xb,
    float* __restrict__ part) {
    __shared__ bf16 As[BM * BK];      // 16 KB
    __shared__ bf16 Bs[NCOLS * BK];   // 16 KB

    const int mt = blockIdx.x;           // 0..63
    const int sp = blockIdx.y;           // 0..SPLITS-1
    const int rbase = mt * BM;
    const size_t kbase = (size_t)sp * KCHUNK;
    const int t = threadIdx.x;
    const int lane = t & 63;
    const int wave = t >> 6;
    const int wr = wave >> 1, wc = wave & 1;   // 2x2 wave grid, 64x64 out each
    const int lm = lane & 15, kq = lane >> 4;

    // staging geometry: chunk c = wave*4+i covers rows 8c..8c+7 (1 KB of LDS).
    // lane covers row 8c + (lane>>3), global col-block (lane&7) ^ (lane>>3 & 7).
    const int lrow = lane >> 3;            // 0..7
    const int jb = (lane & 7) ^ lrow;      // swizzled global col block (8 elems)

    f32x4 acc[4][4];
    const f32x4 zero = {0.f, 0.f, 0.f, 0.f};
#pragma unroll
    for (int mi = 0; mi < 4; mi++)
#pragma unroll
        for (int ni = 0; ni < 4; ni++) acc[mi][ni] = zero;

    for (int kk = 0; kk < KCHUNK; kk += BK) {
#pragma unroll
        for (int i = 0; i < 4; i++) {
            const int c = wave * 4 + i;          // 0..15
            const int row = 8 * c + lrow;        // 0..127
            load_lds16(&Lb[(size_t)(rbase + row) * N_DIM + kbase + kk + jb * 8],
                       &As[c * 512]);
            load_lds16(&Xb[(size_t)row * N_DIM + kbase + kk + jb * 8],
                       &Bs[c * 512]);
        }
        __syncthreads();   // drains vmcnt(0): LDS tiles ready

#pragma unroll
        for (int ks = 0; ks < 2; ks++) {
            bf16x8 af[4], bfr[4];
#pragma unroll
            for (int mi = 0; mi < 4; mi++) {
                int r = wr * 64 + mi * 16 + lm;
                int cb = (kq + 4 * ks) ^ (lm & 7);
                af[mi] = *(const bf16x8*)(&As[r * BK + cb * 8]);
            }
#pragma unroll
            for (int ni = 0; ni < 4; ni++) {
                int r = wc * 64 + ni * 16 + lm;
                int cb = (kq + 4 * ks) ^ (lm & 7);
                bfr[ni] = *(const bf16x8*)(&Bs[r * BK + cb * 8]);
            }
#pragma unroll
            for (int mi = 0; mi < 4; mi++)
#pragma unroll
                for (int ni = 0; ni < 4; ni++)
                    acc[mi][ni] = __builtin_amdgcn_mfma_f32_16x16x32_bf16(
                        af[mi], bfr[ni], acc[mi][ni], 0, 0, 0);
        }
        __syncthreads();   // all reads done before next overwrite
    }

    // epilogue: C/D layout col=lane&15, row=(lane>>4)*4+reg  [m89/m91]
    float* P = part + (size_t)sp * N_DIM * NCOLS;
#pragma unroll
    for (int mi = 0; mi < 4; mi++) {
        int row0 = rbase + wr * 64 + mi * 16 + kq * 4;
#pragma unroll
        for (int ni = 0; ni < 4; ni++) {
            int col = wc * 64 + ni * 16 + lm;
#pragma unroll
            for (int r = 0; r < 4; r++)
                P[(size_t)(row0 + r) * NCOLS + col] = acc[mi][ni][r];
        }
    }
}

// ---------------- combine: Y = sum partials; out += Y . w_eff[pass]; XbNext = bf16(Y^T) ----
__global__ __launch_bounds__(256) void combine_kernel(
    const float* __restrict__ part, const float* __restrict__ w,
    float* __restrict__ out, bf16* __restrict__ XbNext, int pass) {
    __shared__ float Yt[128 * 66];     // transposed tile [col][row], pad 66
    __shared__ float weff[32 * 64];
    int t = threadIdx.x;
    int n0 = blockIdx.x * 64;

    for (int i = t; i < 2048; i += 256) {
        float v;
        if (pass == 1)      v = w[1 * 2048 + i] - w[3 * 2048 + i];
        else if (pass == 2) v = 2.f * w[2 * 2048 + i];
        else                v = 2.f * w[3 * 2048 + i];
        weff[i] = v;
    }
    // phase A: sum SPLITS partials, store transposed into LDS
    for (int slot = t; slot < 2048; slot += 256) {
        int row = slot >> 5;       // 0..63
        int c4 = slot & 31;        // float4 col group
        float4 s = {0.f, 0.f, 0.f, 0.f};
#pragma unroll
        for (int sp = 0; sp < SPLITS; sp++) {
            const float4 v = *(const float4*)(
                &part[(size_t)sp * N_DIM * NCOLS + (size_t)(n0 + row) * NCOLS + c4 * 4]);
            s.x += v.x; s.y += v.y; s.z += v.z; s.w += v.w;
        }
        Yt[(c4 * 4 + 0) * 66 + row] = s.x;
        Yt[(c4 * 4 + 1) * 66 + row] = s.y;
        Yt[(c4 * 4 + 2) * 66 + row] = s.z;
        Yt[(c4 * 4 + 3) * 66 + row] = s.w;
    }
    __syncthreads();
    // phase B: bf16 X^T for next pass
    if (pass < 3) {
        int c = t >> 1;
        int nh = (t & 1) * 32;
#pragma unroll
        for (int v4 = 0; v4 < 4; v4++) {
            union { uint4 u; unsigned short s[8]; } pk;
#pragma unroll
            for (int j = 0; j < 8; j++)
                pk.s[j] = f2bf_bits(Yt[c * 66 + nh + v4 * 8 + j]);
            *(uint4*)(&XbNext[(size_t)c * N_DIM + n0 + nh + v4 * 8]) = pk.u;
        }
    }
    // phase C: out[b, n0+n, fo] += sum_fi Y[n, b*32+fi] * weff[fi][fo]
    int b = t >> 6, fo = t & 63;
    for (int n = 0; n < 64; n++) {
        size_t oidx = ((size_t)b * N_DIM + n0 + n) * 64 + fo;
        float accv = out[oidx];
#pragma unroll
        for (int fi = 0; fi < 32; fi++)
            accv += Yt[(b * 32 + fi) * 66 + n] * weff[fi * 64 + fo];
        out[oidx] = accv;
    }
}

extern "C" void kernel_launch(void* const* d_in, const int* in_sizes, int n_in,
                              void* d_out, int out_size, void* d_ws, size_t ws_size,
                              hipStream_t stream) {
    const float* x    = (const float*)d_in[0];   // [4,8192,32]
    const float* L    = (const float*)d_in[1];   // [8192,8192]
    const float* w    = (const float*)d_in[2];   // [4,32,64]
    const float* bias = (const float*)d_in[3];   // [1,8192,64]
    float* out = (float*)d_out;                  // [4,8192,64]

    char* ws = (char*)d_ws;                          // ws_size ~1 GB (observed)
    bf16* Lb   = (bf16*)ws;                          // 128 MB bf16 L
    bf16* XbA  = (bf16*)(ws + (128ull << 20));       // 2 MB  (X^T bf16)
    bf16* XbB  = (bf16*)(ws + (130ull << 20));       // 2 MB
    float* part = (float*)(ws + (132ull << 20));     // SPLITS * 4 MB = 32 MB

    convert_L_kernel<<<(N_DIM * (size_t)N_DIM) / (4 * 256), 256, 0, stream>>>(L, Lb);
    pack_x_kernel<<<(NCOLS * N_DIM) / 256, 256, 0, stream>>>(x, XbA);
    init_out_kernel<<<(4 * N_DIM) / 16, 256, 0, stream>>>(x, w, bias, out);

    dim3 ggrid(N_DIM / BM, SPLITS);   // 64 x 8 = 512 WGs, 2/CU
    // pass 1: Y = L x
    gemm_kernel<<<ggrid, 256, 0, stream>>>(Lb, XbA, part);
    combine_kernel<<<N_DIM / 64, 256, 0, stream>>>(part, w, out, XbB, 1);
    // pass 2: Y = L^2 x
    gemm_kernel<<<ggrid, 256, 0, stream>>>(Lb, XbB, part);
    combine_kernel<<<N_DIM / 64, 256, 0, stream>>>(part, w, out, XbA, 2);
    // pass 3: Y = L^3 x
    gemm_kernel<<<ggrid, 256, 0, stream>>>(Lb, XbA, part);
    combine_kernel<<<N_DIM / 64, 256, 0, stream>>>(part, w, out, XbA, 3);
}